// Round 6
// baseline (7821.046 us; speedup 1.0000x reference)
//
#include <hip/hip_runtime.h>
#include <hip/hip_bf16.h>
#include <stdint.h>

#define BB   64
#define TT   2048
#define II   256
#define HH   256
#define G4   1024   // 4*H
#define NC   10

typedef _Float16 half2v __attribute__((ext_vector_type(2)));
typedef _Float16 half8v __attribute__((ext_vector_type(8)));
typedef float    float4v __attribute__((ext_vector_type(4)));

__device__ __forceinline__ float fdot2(uint32_t w, uint32_t h, float acc) {
  return __builtin_amdgcn_fdot2(__builtin_bit_cast(half2v, w),
                                __builtin_bit_cast(half2v, h), acc, false);
}
__device__ __forceinline__ float sigmf(float v) { return 1.f / (1.f + __expf(-v)); }
__device__ __forceinline__ float tanhf2(float v) { float e = __expf(2.f * v); return 1.f - 2.f / (e + 1.f); }

// quad butterfly sum (VALU DPP, stays off the DS pipe)
__device__ __forceinline__ float qred(float v) {
  int a = __builtin_amdgcn_update_dpp(0, __builtin_bit_cast(int, v), 0xB1, 0xF, 0xF, true);
  float v2 = v + __builtin_bit_cast(float, a);
  int b = __builtin_amdgcn_update_dpp(0, __builtin_bit_cast(int, v2), 0x4E, 0xF, 0xF, true);
  return v2 + __builtin_bit_cast(float, b);
}

// Barrier WITHOUT vmcnt drain: global prefetches (xpk + weight tail) stay in
// flight across the barrier; only LDS (h ping-pong) is ordered.
__device__ __forceinline__ void bar_lds() {
  asm volatile("s_waitcnt lgkmcnt(0)\n\ts_barrier" ::: "memory");
}

// ---------------------------------------------------------------------------
// K0a: WcT[g][i] = sum_j key[i][j] * W_ih[g][j]  (f16), biasc[g] = b_ih+b_hh
// ---------------------------------------------------------------------------
__global__ __launch_bounds__(1024) void prep_wc(
    const float* __restrict__ key, const float* __restrict__ Wih,
    const float* __restrict__ bih, const float* __restrict__ bhh,
    _Float16* __restrict__ WcT, float* __restrict__ biasc) {
  __shared__ float krow[II];
  const int i = blockIdx.x;
  const int g = threadIdx.x;
  if (g < II) krow[g] = key[(size_t)i * II + g];
  __syncthreads();
  const float4* w4 = (const float4*)(Wih + (size_t)g * II);
  float acc = 0.f;
#pragma unroll 8
  for (int j = 0; j < II / 4; ++j) {
    float4 w = w4[j];
    acc += w.x * krow[4 * j] + w.y * krow[4 * j + 1] + w.z * krow[4 * j + 2] + w.w * krow[4 * j + 3];
  }
  WcT[(size_t)g * II + i] = (_Float16)acc;
  if (i == 0) biasc[g] = bih[g] + bhh[g];
}

// ---------------------------------------------------------------------------
// K0c: pack W_hh for the quad-K-split LSTM (layout identical to R5).
// Thread t = 4q+s (t<512): quad q owns h-indices {2q,2q+1} (8 gate rows),
// lane s owns kpair slice [32s,32s+32) = h-chunks 8s..8s+7, iterated in
// rotated order c_j = 8s + ((j+2s)&7) for bank-conflict-free broadcast.
// Slot (j,r): uint4 = kpairs 4c_j..4c_j+3 of row(r) = 2q+(r&1)+256*(r>>1).
//   j<6  -> wrg4[(j*8+r)*512+t]   (register-resident)
//   j>=6 -> wtl[((j-6)*8+r)*512+t] (L2-resident, read per step via vmcnt)
// ---------------------------------------------------------------------------
__global__ __launch_bounds__(256) void prep_whh(
    const float* __restrict__ Whh, uint4* __restrict__ wrg4, uint4* __restrict__ wtl) {
  const int id = blockIdx.x * 256 + threadIdx.x;   // 32768 = 64 slots * 512 t
  const int t = id & 511;
  const int slot = id >> 9;                         // 0..63
  const int j = slot >> 3, r = slot & 7;
  const int q = t >> 2, s = t & 3;
  const int c = 8 * s + ((j + 2 * s) & 7);
  const int row = 2 * q + (r & 1) + 256 * (r >> 1);
  uint32_t d[4];
#pragma unroll
  for (int k = 0; k < 4; ++k) {
    const int kp = 4 * c + k;
    half2v h = {(_Float16)Whh[(size_t)row * HH + 2 * kp],
                (_Float16)Whh[(size_t)row * HH + 2 * kp + 1]};
    d[k] = __builtin_bit_cast(uint32_t, h);
  }
  uint4 v = {d[0], d[1], d[2], d[3]};
  if (j < 6) wrg4[(j * 8 + r) * 512 + t] = v;
  else       wtl[((j - 6) * 8 + r) * 512 + t] = v;
}

// ---------------------------------------------------------------------------
// K1: packed x-projection GEMM. Logical x_proj[m][col], col = h + 256*gate.
// Stored per row m as 1024 f16; slot = (h>>1)*8 + (h&1)*4 + gate, so quad q's
// 8 values {i,f,g,o}x{h=2q,2q+1} are f16[8q..8q+7] = one aligned uint4.
// ---------------------------------------------------------------------------
__global__ __launch_bounds__(256) void gemm_xproj(
    const float* __restrict__ x, const _Float16* __restrict__ WcT,
    const float* __restrict__ biasc, _Float16* __restrict__ xpk) {
  __shared__ __align__(16) _Float16 Asm[128][40];
  __shared__ __align__(16) _Float16 Bsm[128][40];
  const int t = threadIdx.x;
  const int n0 = blockIdx.x * 128;
  const int m0 = blockIdx.y * 128;
  const int r = t >> 1;
  const int hoff = (t & 1) * 16;
  const int lane = t & 63, wave = t >> 6;
  const int quad = lane >> 4, l15 = lane & 15;
  const int mh = (wave & 1) * 64, nh = (wave >> 1) * 64;
  float4v zero = {0.f, 0.f, 0.f, 0.f};
  float4v acc[4][4];
#pragma unroll
  for (int a = 0; a < 4; ++a)
#pragma unroll
    for (int b = 0; b < 4; ++b) acc[a][b] = zero;

  for (int kt = 0; kt < 8; ++kt) {
    const int k0 = kt * 32;
    const float4* xa = (const float4*)(x + (size_t)(m0 + r) * II + k0 + hoff);
    float4 f0 = xa[0], f1 = xa[1], f2 = xa[2], f3 = xa[3];
    half8v lo = {(_Float16)f0.x, (_Float16)f0.y, (_Float16)f0.z, (_Float16)f0.w,
                 (_Float16)f1.x, (_Float16)f1.y, (_Float16)f1.z, (_Float16)f1.w};
    half8v hi = {(_Float16)f2.x, (_Float16)f2.y, (_Float16)f2.z, (_Float16)f2.w,
                 (_Float16)f3.x, (_Float16)f3.y, (_Float16)f3.z, (_Float16)f3.w};
    const half8v* bsrc = (const half8v*)(WcT + (size_t)(n0 + r) * II + k0 + hoff);
    half8v b0 = bsrc[0], b1 = bsrc[1];
    *(half8v*)&Asm[r][hoff]     = lo;
    *(half8v*)&Asm[r][hoff + 8] = hi;
    *(half8v*)&Bsm[r][hoff]     = b0;
    *(half8v*)&Bsm[r][hoff + 8] = b1;
    __syncthreads();
    half8v af[4], bf[4];
#pragma unroll
    for (int mt = 0; mt < 4; ++mt) af[mt] = *(const half8v*)&Asm[mh + mt * 16 + l15][quad * 8];
#pragma unroll
    for (int nt = 0; nt < 4; ++nt) bf[nt] = *(const half8v*)&Bsm[nh + nt * 16 + l15][quad * 8];
#pragma unroll
    for (int mt = 0; mt < 4; ++mt)
#pragma unroll
      for (int nt = 0; nt < 4; ++nt)
        acc[mt][nt] = __builtin_amdgcn_mfma_f32_16x16x32_f16(af[mt], bf[nt], acc[mt][nt], 0, 0, 0);
    __syncthreads();
  }
  _Float16* dst = xpk;
#pragma unroll
  for (int nt = 0; nt < 4; ++nt) {
    const int col = n0 + nh + nt * 16 + l15;
    const float bias = biasc[col];
    const int h = col & 255, gate = col >> 8;
    const int cslot = (h >> 1) * 8 + (h & 1) * 4 + gate;
#pragma unroll
    for (int mt = 0; mt < 4; ++mt) {
      const int mrow = m0 + mh + mt * 16 + quad * 4;
#pragma unroll
      for (int j = 0; j < 4; ++j)
        dst[(size_t)(mrow + j) * 1024 + cslot] = (_Float16)(acc[mt][nt][j] + bias);
    }
  }
}

// ---------------------------------------------------------------------------
// K2: sequential LSTM, quad-K-split. 64 WGs x 512 threads (2 waves/SIMD).
// Thread 4q+s: partial dots over kpair slice s for the 8 gate rows of
// h-indices {2q,2q+1}; DPP quad butterfly combines; gates thread-local.
// Weights: 192 dwords/thread in regs; 16-uint4 tail read per step from
// GLOBAL (L2-hot, shared by all WGs) on the vmcnt pipe -> issued at loop
// top, never drained by the lgkm-only barrier, pipelines across steps.
// LDS holds ONLY the 1 KB h ping-pong; per-step DS = 8 rolling h-reads
// (distance-2, conflict-free rotation) + 1 write.
// ---------------------------------------------------------------------------
__global__ __launch_bounds__(512, 2) void lstm_seq(
    const uint32_t* __restrict__ xpk, const uint4* __restrict__ wrg4,
    const uint4* __restrict__ wtl, float* __restrict__ hfin) {
  __shared__ __align__(16) uint32_t hbuf[2][128];   // ping-pong h (f16 pairs)
  const int t = threadIdx.x, blk = blockIdx.x;
  const int q = t >> 2, s = t & 3;

  uint4 wv[48];
#pragma unroll
  for (int k = 0; k < 48; ++k) wv[k] = wrg4[k * 512 + t];
  if (t < 128) { hbuf[0][t] = 0; hbuf[1][t] = 0; }

  // per-lane rotated chunk byte offsets (conflict-free h broadcast)
  int coff[8];
#pragma unroll
  for (int j = 0; j < 8; ++j) coff[j] = (8 * s + ((j + 2 * s) & 7)) * 16;

  float c0 = 0.f, c1 = 0.f, h0v = 0.f, h1v = 0.f;
  const uint32_t* xp = xpk + (size_t)blk * TT * 512;
  uint4 xn = *(const uint4*)(xp + 4 * q);
  const uint4* wt = wtl + t;
  __syncthreads();

  for (int ts = 0; ts < TT; ++ts) {
    const uint4 xw = xn;
    xn = *(const uint4*)(xp + (size_t)((ts < TT - 1) ? ts + 1 : ts) * 512 + 4 * q);
    // tail group 6: issue early, consumed after ~6 dot-groups (~800 cyc cover)
    uint4 tw6[8];
#pragma unroll
    for (int r = 0; r < 8; ++r) tw6[r] = wt[r * 512];
    const char* hb = (const char*)hbuf[ts & 1];
    uint4 hr[8];
    hr[0] = *(const uint4*)(hb + coff[0]);
    hr[1] = *(const uint4*)(hb + coff[1]);
    float acc[8] = {0.f, 0.f, 0.f, 0.f, 0.f, 0.f, 0.f, 0.f};
    uint4 tw7[8];
#pragma unroll
    for (int j = 0; j < 6; ++j) {
      if (j < 6) hr[(j + 2) & 7] = *(const uint4*)(hb + coff[(j + 2) & 7]);
      if (j == 3) {   // tail group 7: ~400 cyc cover before j=7 consumption
#pragma unroll
        for (int r = 0; r < 8; ++r) tw7[r] = wt[(8 + r) * 512];
      }
#pragma unroll
      for (int r = 0; r < 8; ++r) {
        uint4 w = wv[j * 8 + r];
        acc[r] = fdot2(w.x, hr[j].x, acc[r]);
        acc[r] = fdot2(w.y, hr[j].y, acc[r]);
        acc[r] = fdot2(w.z, hr[j].z, acc[r]);
        acc[r] = fdot2(w.w, hr[j].w, acc[r]);
      }
    }
#pragma unroll
    for (int r = 0; r < 8; ++r) {
      uint4 w = tw6[r];
      acc[r] = fdot2(w.x, hr[6].x, acc[r]);
      acc[r] = fdot2(w.y, hr[6].y, acc[r]);
      acc[r] = fdot2(w.z, hr[6].z, acc[r]);
      acc[r] = fdot2(w.w, hr[6].w, acc[r]);
    }
#pragma unroll
    for (int r = 0; r < 8; ++r) {
      uint4 w = tw7[r];
      acc[r] = fdot2(w.x, hr[7].x, acc[r]);
      acc[r] = fdot2(w.y, hr[7].y, acc[r]);
      acc[r] = fdot2(w.z, hr[7].z, acc[r]);
      acc[r] = fdot2(w.w, hr[7].w, acc[r]);
    }
    // quad reduction (r: 0=i0 1=i1 2=f0 3=f1 4=g0 5=g1 6=o0 7=o1)
    float red[8];
#pragma unroll
    for (int r = 0; r < 8; ++r) red[r] = qred(acc[r]);
    half2v xa = __builtin_bit_cast(half2v, xw.x);   // i0,f0
    half2v xb = __builtin_bit_cast(half2v, xw.y);   // g0,o0
    half2v xc = __builtin_bit_cast(half2v, xw.z);   // i1,f1
    half2v xd = __builtin_bit_cast(half2v, xw.w);   // g1,o1
    float i0 = sigmf(red[0] + (float)xa.x);
    float f0 = sigmf(red[2] + (float)xa.y);
    float g0 = tanhf2(red[4] + (float)xb.x);
    float o0 = sigmf(red[6] + (float)xb.y);
    float i1 = sigmf(red[1] + (float)xc.x);
    float f1 = sigmf(red[3] + (float)xc.y);
    float g1 = tanhf2(red[5] + (float)xd.x);
    float o1 = sigmf(red[7] + (float)xd.y);
    c0 = f0 * c0 + i0 * g0;
    c1 = f1 * c1 + i1 * g1;
    h0v = o0 * tanhf2(c0);
    h1v = o1 * tanhf2(c1);
    if (s == 0) {
      half2v hp = {(_Float16)h0v, (_Float16)h1v};
      hbuf[(ts + 1) & 1][q] = __builtin_bit_cast(uint32_t, hp);
    }
    bar_lds();
  }
  if (s == 0) {
    hfin[(size_t)blk * HH + 2 * q]     = h0v;
    hfin[(size_t)blk * HH + 2 * q + 1] = h1v;
  }
}

// ---------------------------------------------------------------------------
// K3: out[b][c] = h_last[b] . W_cls[c] + b_cls[c]
// ---------------------------------------------------------------------------
__global__ __launch_bounds__(256) void cls_k(
    const float* __restrict__ hfin, const float* __restrict__ Wcls,
    const float* __restrict__ bcls, float* __restrict__ out) {
  __shared__ float part[4][NC];
  const int b = blockIdx.x, tid = threadIdx.x;
  const int lane = tid & 63, wave = tid >> 6;
  float hv = hfin[(size_t)b * HH + tid];
#pragma unroll
  for (int c = 0; c < NC; ++c) {
    float p = hv * Wcls[c * HH + tid];
#pragma unroll
    for (int off = 32; off >= 1; off >>= 1) p += __shfl_down(p, off, 64);
    if (lane == 0) part[wave][c] = p;
  }
  __syncthreads();
  if (tid < NC) {
    out[(size_t)b * NC + tid] =
        part[0][tid] + part[1][tid] + part[2][tid] + part[3][tid] + bcls[tid];
  }
}

// ---------------------------------------------------------------------------
extern "C" void kernel_launch(void* const* d_in, const int* in_sizes, int n_in,
                              void* d_out, int out_size, void* d_ws, size_t ws_size,
                              hipStream_t stream) {
  (void)in_sizes; (void)n_in; (void)out_size; (void)ws_size;
  const float* x    = (const float*)d_in[0];
  const float* key  = (const float*)d_in[1];
  const float* Wih  = (const float*)d_in[2];
  const float* Whh  = (const float*)d_in[3];
  const float* bih  = (const float*)d_in[4];
  const float* bhh  = (const float*)d_in[5];
  const float* Wcls = (const float*)d_in[6];
  const float* bcls = (const float*)d_in[7];
  float* out = (float*)d_out;

  char* ws = (char*)d_ws;
  size_t off = 0;
  uint32_t* xpk = (uint32_t*)(ws + off); off += (size_t)BB * TT * 512 * 4;  // 268 MB
  uint4* wrg4   = (uint4*)(ws + off);    off += (size_t)48 * 512 * 16;      // 384 KB
  uint4* wtl    = (uint4*)(ws + off);    off += (size_t)16 * 512 * 16;      // 128 KB
  _Float16* WcT = (_Float16*)(ws + off); off += (size_t)G4 * II * 2;
  float* biasc  = (float*)(ws + off);    off += (size_t)G4 * 4;
  float* hfin   = (float*)(ws + off);    off += (size_t)BB * HH * 4;

  hipLaunchKernelGGL(prep_wc,  dim3(II),  dim3(G4),  0, stream, key, Wih, bih, bhh, WcT, biasc);
  hipLaunchKernelGGL(prep_whh, dim3(128), dim3(256), 0, stream, Whh, wrg4, wtl);
  hipLaunchKernelGGL(gemm_xproj, dim3(G4 / 128, (BB * TT) / 128), dim3(256), 0, stream,
                     x, WcT, biasc, (_Float16*)xpk);
  hipLaunchKernelGGL(lstm_seq, dim3(BB), dim3(512), 0, stream, xpk, wrg4, wtl, hfin);
  hipLaunchKernelGGL(cls_k,    dim3(BB), dim3(256), 0, stream, hfin, Wcls, bcls, out);
}